// Round 19
// baseline (98.055 us; speedup 1.0000x reference)
//
#include <hip/hip_runtime.h>
#include <hip/hip_fp16.h>

constexpr int Hh = 320, Ww = 320, Cc = 32, Bb = 4, Nn = 20000;
constexpr int HWp = Hh * Ww;

// DPP quad_perm helpers (VALU lane exchange within 4-lane quads; no DS pipe).
template <int CTRL>
__device__ __forceinline__ float dpp_mov(float x) {
  return __int_as_float(
      __builtin_amdgcn_update_dpp(0, __float_as_int(x), CTRL, 0xF, 0xF, true));
}
__device__ __forceinline__ float quad_add_xor1(float x) {
  return x + dpp_mov<0xB1>(x);
}
__device__ __forceinline__ float quad_add_xor2(float x) {
  return x + dpp_mov<0x4E>(x);
}

union H4 { __half2 h2[2]; float2 f2; };
union H8 { __half2 h2[4]; float4 f4; };

__device__ __forceinline__ void store_h4(__half* p, float4 v) {
  H4 u;
  u.h2[0] = __floats2half2_rn(v.x, v.y);
  u.h2[1] = __floats2half2_rn(v.z, v.w);
  *(float2*)p = u.f2;
}
__device__ __forceinline__ float4 cvt_h4(float2 raw) {
  H4 u;
  u.f2 = raw;
  float2 lo = __half22float2(u.h2[0]), hi = __half22float2(u.h2[1]);
  return make_float4(lo.x, lo.y, hi.x, hi.y);
}

// prep: blocks [0,800) fill grids with -1; blocks 800/801: per-dir fold
// constants. Wvo_h = ow[:,16h:16h+16] @ wv[16h:16h+16,:] (PER-HEAD fold of the
// output projection into V -- valid because each head has its own softmax).
// pv2[h][l][c] = pos_l @ Wvo_h.T ; obias2[c] = out_b[c] + sum_j bv[j]*ow[c,j].
__global__ __launch_bounds__(256) void prep_k(
    int* __restrict__ grids, const float* __restrict__ pos,
    const float* __restrict__ in_w1, const float* __restrict__ in_b1,
    const float* __restrict__ out_w1, const float* __restrict__ out_b1,
    const float* __restrict__ in_w2, const float* __restrict__ in_b2,
    const float* __restrict__ out_w2, const float* __restrict__ out_b2,
    float* __restrict__ Wvo, float* __restrict__ pv2g,
    float* __restrict__ obias2) {
  int bx = blockIdx.x;
  if (bx < 800) {
    int i = bx * 256 + threadIdx.x;  // 800*256 int4 = 2*4*HWp ints exactly
    ((int4*)grids)[i] = make_int4(-1, -1, -1, -1);
    return;
  }
  int dir = bx - 800;
  const float* iw = dir == 0 ? in_w1 : in_w2;
  const float* ib = dir == 0 ? in_b1 : in_b2;
  const float* owp = dir == 0 ? out_w1 : out_w2;
  const float* obp = dir == 0 ? out_b1 : out_b2;
  __shared__ float sow[1024], swv[1024], sW[2048];
  int t = threadIdx.x;
  for (int i = t; i < 1024; i += 256) {
    sow[i] = owp[i];
    swv[i] = iw[2 * Cc * Cc + i];  // wv rows of in_w
  }
  __syncthreads();
  for (int e = t; e < 2048; e += 256) {
    int h = e >> 10, idx = e & 1023;
    int c = idx >> 5, j = idx & 31;
    float acc = 0.f;
    for (int jj = 0; jj < 16; jj++)
      acc += sow[c * 32 + h * 16 + jj] * swv[(h * 16 + jj) * 32 + j];
    sW[e] = acc;
    Wvo[dir * 2048 + e] = acc;
  }
  __syncthreads();
  for (int e = t; e < 576; e += 256) {  // 2 heads x 9 slots x 32 ch
    int h = e / 288, rem = e - h * 288;
    int l = rem >> 5, c = rem & 31;
    float acc = 0.f;
    for (int j = 0; j < 32; j++) acc += pos[l * 32 + j] * sW[h * 1024 + c * 32 + j];
    pv2g[dir * 576 + e] = acc;
  }
  if (t < Cc) {
    float acc = obp[t];
    for (int j = 0; j < 32; j++) acc += ib[2 * Cc + j] * sow[t * 32 + j];
    obias2[dir * Cc + t] = acc;
  }
}

// Fused: blocks [0, PROJ_TOTAL) = Q/K/V0f/V1f projection (4 pts/thread, fp16
// stores; V0f/V1f are the per-head folded V); rest = build_grid (pre-filled).
constexpr int PROJ_BLOCKS_PER_SB = 157;              // ceil(20000/128)
constexpr int PROJ_TOTAL = PROJ_BLOCKS_PER_SB * 8;   // 1256
constexpr int BUILD_BLOCKS = 625;                    // 160000/256 exact

__global__ __launch_bounds__(256) void project_build_k(
    const float* __restrict__ li_feats, const float* __restrict__ ra_feats,
    const int* __restrict__ li_coors, const int* __restrict__ ra_coors,
    const float* __restrict__ in_w1, const float* __restrict__ in_b1,
    const float* __restrict__ in_w2, const float* __restrict__ in_b2,
    const float* __restrict__ Wvo,
    __half* __restrict__ Qh, __half* __restrict__ Kp,
    __half* __restrict__ V0, __half* __restrict__ V1,
    int* __restrict__ grids) {
  int bx = blockIdx.x;
  if (bx >= PROJ_TOTAL) {
    int idx = (bx - PROJ_TOTAL) * 256 + threadIdx.x;  // [0, 160000) exact
    int src = idx / (Bb * Nn);
    int r = idx - src * (Bb * Nn);
    int b = r / Nn, n = r - b * Nn;
    const int* c = (src == 0 ? li_coors : ra_coors) + ((size_t)b * Nn + n) * 2;
    grids[((size_t)src * Bb + b) * HWp + c[0] * Ww + c[1]] = n;
    return;
  }
  int sb = bx / PROJ_BLOCKS_PER_SB;
  int blk = bx - sb * PROJ_BLOCKS_PER_SB;
  int src = sb >> 2, b = sb & 3;
  // weights transposed, rows padded to 36 floats (9 float4) for bank spread
  __shared__ __align__(16) float wqT[32 * 36];
  __shared__ __align__(16) float wkT[32 * 36];
  __shared__ __align__(16) float w0T[32 * 36];
  __shared__ __align__(16) float w1T[32 * 36];
  __shared__ float bq[Cc];
  const float* wA = src == 0 ? in_w1 : in_w2;  // q weights: own direction
  const float* bA = src == 0 ? in_b1 : in_b2;
  const float* wB = src == 0 ? in_w2 : in_w1;  // k weights: other direction
  int dirkv = 1 - src;
  const float* Wf = Wvo + (size_t)dirkv * 2048;  // per-head folded V weights
  int t = threadIdx.x;
  for (int i = t; i < Cc * Cc; i += 256) {
    int c = i >> 5, j = i & 31;
    wqT[j * 36 + c] = wA[i];
    wkT[j * 36 + c] = wB[Cc * Cc + i];
    w0T[j * 36 + c] = Wf[i];
    w1T[j * 36 + c] = Wf[1024 + i];
  }
  if (t < Cc) bq[t] = bA[t];
  __syncthreads();
  int quad = t >> 3, c4 = t & 7;
  int n0 = blk * 128 + quad * 4;
  if (n0 + 4 > Nn) n0 = Nn - 4;  // tail clamp: redundant idempotent work
  const float* f = (src == 0 ? li_feats : ra_feats) + ((size_t)b * Nn + n0) * Cc;
  const float4* wq4 = (const float4*)wqT;
  const float4* wk4 = (const float4*)wkT;
  const float4* w04 = (const float4*)w0T;
  const float4* w14 = (const float4*)w1T;
  float4 bq4 = *(const float4*)(bq + c4 * 4);
  float4 aq[4], ak[4], a0[4], a1[4];
#pragma unroll
  for (int i = 0; i < 4; i++) {
    aq[i] = bq4;
    ak[i] = make_float4(0.f, 0.f, 0.f, 0.f);
    a0[i] = make_float4(0.f, 0.f, 0.f, 0.f);
    a1[i] = make_float4(0.f, 0.f, 0.f, 0.f);
  }
#pragma unroll
  for (int j4 = 0; j4 < 8; j4++) {
    float fjs[4][4];
#pragma unroll
    for (int i = 0; i < 4; i++) {
      float4 v = ((const float4*)(f + i * Cc))[j4];
      fjs[i][0] = v.x; fjs[i][1] = v.y; fjs[i][2] = v.z; fjs[i][3] = v.w;
    }
#pragma unroll
    for (int u = 0; u < 4; u++) {
      int j = j4 * 4 + u;
      float4 q4 = wq4[j * 9 + c4];
      float4 k4 = wk4[j * 9 + c4];
      float4 v04 = w04[j * 9 + c4];
      float4 v14 = w14[j * 9 + c4];
#pragma unroll
      for (int i = 0; i < 4; i++) {
        float fj = fjs[i][u];
        aq[i].x += fj * q4.x; aq[i].y += fj * q4.y;
        aq[i].z += fj * q4.z; aq[i].w += fj * q4.w;
        ak[i].x += fj * k4.x; ak[i].y += fj * k4.y;
        ak[i].z += fj * k4.z; ak[i].w += fj * k4.w;
        a0[i].x += fj * v04.x; a0[i].y += fj * v04.y;
        a0[i].z += fj * v04.z; a0[i].w += fj * v04.w;
        a1[i].x += fj * v14.x; a1[i].y += fj * v14.y;
        a1[i].z += fj * v14.z; a1[i].w += fj * v14.w;
      }
    }
  }
  size_t qbase = (((size_t)src * Bb + b) * Nn + n0) * Cc + c4 * 4;
  size_t kvbase = (((size_t)dirkv * Bb + b) * Nn + n0) * Cc + c4 * 4;
#pragma unroll
  for (int i = 0; i < 4; i++) {
    store_h4(Qh + qbase + i * Cc, aq[i]);
    store_h4(Kp + kvbase + i * Cc, ak[i]);
    store_h4(V0 + kvbase + i * Cc, a0[i]);
    store_h4(V1 + kvbase + i * Cc, a1[i]);
  }
}

// 8-lane-per-point attention with folded output projection, PLUS co-scheduled
// empty-pixel zero-fill blocks (bx >= ATTN_BLOCKS): attention is latency-bound
// with idle memory BW; the fill blocks (84 MB of the output write) ride in the
// idle slots. XCD pinning preserved (ATTN_BLOCKS % 8 == 0).
constexpr int ATTN_BLOCKS = (Nn / 32) * 8;   // 5000
constexpr int FILL_BLOCKS = (HWp / 256) * 8; // 3200

__global__ __launch_bounds__(256) void attn8_k(
    const int* __restrict__ li_coors, const int* __restrict__ ra_coors,
    const int* __restrict__ grids, const __half* __restrict__ Qh,
    const __half* __restrict__ Kp, const __half* __restrict__ V0,
    const __half* __restrict__ V1, const float* __restrict__ pv2g,
    const float* __restrict__ in_b1, const float* __restrict__ in_b2,
    const float* __restrict__ obias2, __half* __restrict__ out_pts,
    float* __restrict__ out) {
  __shared__ __align__(16) float spv[576];  // [h][l][c]
  __shared__ float sbk[Cc], sob[Cc];
  int t = threadIdx.x;
  if (blockIdx.x >= ATTN_BLOCKS) {
    // ---- zero-fill role: write zeros to all 32 channels of empty pixels
    int fb = blockIdx.x - ATTN_BLOCKS;
    int db = fb & 7;   // == blockIdx.x & 7 (ATTN_BLOCKS % 8 == 0) -> XCD-pinned
    int bx = fb >> 3;  // pixel tile [0, 400)
    int dir = db >> 2, b = db & 3;
    int p = bx * 256 + t;
    const int* gq = grids + ((size_t)dir * Bb + b) * HWp;
    int se = gq[p];
    if (se < 0) {
      float* ob = out + (((size_t)dir * Bb + b) * Cc) * HWp + p;
#pragma unroll
      for (int c = 0; c < Cc; c++) ob[(size_t)c * HWp] = 0.f;
    }
    return;
  }
  int db = blockIdx.x & 7;   // XCD-pinned (dir,b)
  int bx = blockIdx.x >> 3;  // point tile [0, 625)
  int dir = db >> 2, b = db & 3;
  const float* ibp = dir == 0 ? in_b1 : in_b2;
  for (int i = t; i < 576; i += 256) spv[i] = pv2g[dir * 576 + i];
  if (t < Cc) {
    sbk[t] = ibp[Cc + t];
    sob[t] = obias2[dir * Cc + t];
  }
  __syncthreads();
  int pt = t >> 3, c4 = t & 7;
  int n = bx * 32 + pt;  // 625*32 == 20000 exact, no tail
  const int2* qcp =
      (const int2*)((dir == 0 ? li_coors : ra_coors) + (size_t)b * Nn * 2);
  int2 yx = qcp[n];
  int y = yx.x, x = yx.y;
  const int* g = grids + ((size_t)(1 - dir) * Bb + b) * HWp;
  const int DY[9] = {0, -1, 1, 0, -1, 1, 0, -1, 1};
  const int DX[9] = {0, 0, 0, 1, 1, 1, -1, -1, -1};
  // ---- phase 1: all 9 sel loads (independent, 1-deep; grid pre-filled)
  int sel[9];
#pragma unroll
  for (int l = 0; l < 9; l++) {
    int cy = y + DY[l], cx = x + DX[l];
    sel[l] = ((unsigned)cy < (unsigned)Hh && (unsigned)cx < (unsigned)Ww)
                 ? g[cy * Ww + cx]
                 : -1;
  }
  // ---- phase 2: issue all K/V0/V1 gathers (raw fp16, 8B/lane; 0 if invalid)
  size_t dbb = ((size_t)dir * Bb + b) * Nn * Cc;
  const __half* Kpb = Kp + dbb;
  const __half* V0b = V0 + dbb;
  const __half* V1b = V1 + dbb;
  float2 kr[9], v0r[9], v1r[9];
#pragma unroll
  for (int l = 0; l < 9; l++) {
    float2 kk = make_float2(0.f, 0.f);  // bit pattern 0 == fp16 zeros
    float2 v0v = make_float2(0.f, 0.f);
    float2 v1v = make_float2(0.f, 0.f);
    int se = sel[l];
    if (se >= 0) {
      size_t o = (size_t)se * Cc + c4 * 4;
      kk = *(const float2*)(Kpb + o);
      v0v = *(const float2*)(V0b + o);
      v1v = *(const float2*)(V1b + o);
    }
    kr[l] = kk;
    v0r[l] = v0v;
    v1r[l] = v1v;
  }
  float4 qh4 = cvt_h4(
      *(const float2*)(Qh + (((size_t)dir * Bb + b) * Nn + n) * Cc + c4 * 4));
  // invalid-slot score: qh . bk over the lane's head (DPP quad reduce)
  float4 bk4 = *(const float4*)(sbk + c4 * 4);
  float pb = qh4.x * bk4.x + qh4.y * bk4.y + qh4.z * bk4.z + qh4.w * bk4.w;
  pb = quad_add_xor1(pb);
  pb = quad_add_xor2(pb);
  // ---- phase 3: scores (own head) from registers
  float s[9];
#pragma unroll
  for (int l = 0; l < 9; l++) {
    float4 k4 = cvt_h4(kr[l]);
    float d = qh4.x * k4.x + qh4.y * k4.y + qh4.z * k4.z + qh4.w * k4.w;
    d = quad_add_xor1(d);
    d = quad_add_xor2(d);
    s[l] = 0.25f * (pb + d);
  }
  // softmax over 9 slots for the lane's head (invalid slots participate: s=pb/4)
  float m = s[0];
#pragma unroll
  for (int l = 1; l < 9; l++) m = fmaxf(m, s[l]);
  float sum = 0.f;
#pragma unroll
  for (int l = 0; l < 9; l++) {
    s[l] = __expf(s[l] - m);
    sum += s[l];
  }
  float rsum = 1.f / sum;
  float aown[9], aoth[9];
#pragma unroll
  for (int l = 0; l < 9; l++) aown[l] = s[l] * rsum;
#pragma unroll
  for (int l = 0; l < 9; l++) aoth[l] = __shfl_xor(aown[l], 4);
  // ---- phase 4: dual-head PV; lane's out channels = [4*c4..). hd = own head.
  int hd = c4 >> 2;
  float4 acc = *(const float4*)(sob + c4 * 4);  // out_b + B0 + B1
  const float* pv0 = spv + 0 * 288 + c4 * 4;
  const float* pv1 = spv + 1 * 288 + c4 * 4;
#pragma unroll
  for (int l = 0; l < 9; l++) {
    if (sel[l] >= 0) {
      float a0w = hd == 0 ? aown[l] : aoth[l];
      float a1w = hd == 0 ? aoth[l] : aown[l];
      float4 v0 = cvt_h4(v0r[l]);
      float4 v1 = cvt_h4(v1r[l]);
      float4 p0 = *(const float4*)(pv0 + l * 32);
      float4 p1 = *(const float4*)(pv1 + l * 32);
      acc.x += a0w * (v0.x + p0.x) + a1w * (v1.x + p1.x);
      acc.y += a0w * (v0.y + p0.y) + a1w * (v1.y + p1.y);
      acc.z += a0w * (v0.z + p0.z) + a1w * (v1.z + p1.z);
      acc.w += a0w * (v0.w + p0.w) + a1w * (v1.w + p1.w);
    }
  }
  store_h4(out_pts + (((size_t)dir * Bb + b) * Nn + n) * Cc + c4 * 4, acc);
}

// Scatter (occupied pixels only; empty pixels zeroed in attn8's fill blocks).
// XCD-partitioned; one thread per canvas pixel; coalesced channel stores.
__global__ __launch_bounds__(256) void scatter_k(
    const int* __restrict__ grids, const __half* __restrict__ out_pts,
    float* __restrict__ out) {
  int db = blockIdx.x & 7;   // XCD-pinned (dir,b)
  int bx = blockIdx.x >> 3;  // pixel tile [0, 400)
  int dir = db >> 2, b = db & 3;
  int p = bx * 256 + threadIdx.x;
  const int* gq = grids + ((size_t)dir * Bb + b) * HWp;
  int se = gq[p];
  if (se < 0) return;  // empty pixels already zero-filled
  float* ob = out + (((size_t)dir * Bb + b) * Cc) * HWp + p;
  const float4* sp =
      (const float4*)(out_pts + (((size_t)dir * Bb + b) * Nn + se) * Cc);
#pragma unroll
  for (int c8 = 0; c8 < 4; c8++) {
    H8 u;
    u.f4 = sp[c8];
#pragma unroll
    for (int k = 0; k < 4; k++) {
      float2 pr = __half22float2(u.h2[k]);
      ob[(size_t)(c8 * 8 + k * 2 + 0) * HWp] = pr.x;
      ob[(size_t)(c8 * 8 + k * 2 + 1) * HWp] = pr.y;
    }
  }
}

extern "C" void kernel_launch(void* const* d_in, const int* in_sizes, int n_in,
                              void* d_out, int out_size, void* d_ws, size_t ws_size,
                              hipStream_t stream) {
  const float* li_feats = (const float*)d_in[0];
  const int* li_coors = (const int*)d_in[1];
  const float* ra_feats = (const float*)d_in[2];
  const int* ra_coors = (const int*)d_in[3];
  const float* pos = (const float*)d_in[4];
  const float* in_w1 = (const float*)d_in[5];
  const float* in_b1 = (const float*)d_in[6];
  const float* out_w1 = (const float*)d_in[7];
  const float* out_b1 = (const float*)d_in[8];
  const float* in_w2 = (const float*)d_in[9];
  const float* in_b2 = (const float*)d_in[10];
  const float* out_w2 = (const float*)d_in[11];
  const float* out_b2 = (const float*)d_in[12];

  char* ws = (char*)d_ws;
  size_t off = 0;
  int* grids = (int*)(ws + off);
  off += (size_t)2 * Bb * HWp * 4;  // 3,276,800 B
  __half* Qh = (__half*)(ws + off);
  off += (size_t)2 * Bb * Nn * Cc * 2;  // 10,240,000 B
  __half* Kp = (__half*)(ws + off);
  off += (size_t)2 * Bb * Nn * Cc * 2;
  __half* V0 = (__half*)(ws + off);
  off += (size_t)2 * Bb * Nn * Cc * 2;
  __half* V1 = (__half*)(ws + off);
  off += (size_t)2 * Bb * Nn * Cc * 2;
  __half* out_pts = (__half*)(ws + off);
  off += (size_t)2 * Bb * Nn * Cc * 2;
  float* Wvo = (float*)(ws + off);
  off += 2 * 2048 * 4;
  float* pv2g = (float*)(ws + off);
  off += 2 * 576 * 4;
  float* obias2 = (float*)(ws + off);
  off += 2 * Cc * 4;  // total ~54.5 MB

  prep_k<<<802, 256, 0, stream>>>(grids, pos, in_w1, in_b1, out_w1, out_b1,
                                  in_w2, in_b2, out_w2, out_b2, Wvo, pv2g,
                                  obias2);
  project_build_k<<<PROJ_TOTAL + BUILD_BLOCKS, 256, 0, stream>>>(
      li_feats, ra_feats, li_coors, ra_coors, in_w1, in_b1, in_w2, in_b2, Wvo,
      Qh, Kp, V0, V1, grids);
  attn8_k<<<ATTN_BLOCKS + FILL_BLOCKS, 256, 0, stream>>>(
      li_coors, ra_coors, grids, Qh, Kp, V0, V1, pv2g, in_b1, in_b2, obias2,
      out_pts, (float*)d_out);
  scatter_k<<<(HWp / 256) * 8, 256, 0, stream>>>(grids, out_pts,
                                                 (float*)d_out);
}

// Round 20
// 87.145 us; speedup vs baseline: 1.1252x; 1.1252x over previous
//
#include <hip/hip_runtime.h>
#include <hip/hip_fp16.h>

constexpr int Hh = 320, Ww = 320, Cc = 32, Bb = 4, Nn = 20000;
constexpr int HWp = Hh * Ww;

// DPP quad_perm helpers (VALU lane exchange within 4-lane quads; no DS pipe).
template <int CTRL>
__device__ __forceinline__ float dpp_mov(float x) {
  return __int_as_float(
      __builtin_amdgcn_update_dpp(0, __float_as_int(x), CTRL, 0xF, 0xF, true));
}
__device__ __forceinline__ float quad_add_xor1(float x) {
  return x + dpp_mov<0xB1>(x);
}
__device__ __forceinline__ float quad_add_xor2(float x) {
  return x + dpp_mov<0x4E>(x);
}

union H4 { __half2 h2[2]; float2 f2; };
union H8 { __half2 h2[4]; float4 f4; };

__device__ __forceinline__ void store_h4(__half* p, float4 v) {
  H4 u;
  u.h2[0] = __floats2half2_rn(v.x, v.y);
  u.h2[1] = __floats2half2_rn(v.z, v.w);
  *(float2*)p = u.f2;
}
__device__ __forceinline__ float4 cvt_h4(float2 raw) {
  H4 u;
  u.f2 = raw;
  float2 lo = __half22float2(u.h2[0]), hi = __half22float2(u.h2[1]);
  return make_float4(lo.x, lo.y, hi.x, hi.y);
}

// prep: blocks [0,800) fill grids with -1; blocks 800/801: per-dir fold
// constants. Wvo_h = ow[:,16h:16h+16] @ wv[16h:16h+16,:] (PER-HEAD fold of the
// output projection into V -- valid because each head has its own softmax).
// pv2[h][l][c] = pos_l @ Wvo_h.T ; obias2[c] = out_b[c] + sum_j bv[j]*ow[c,j].
__global__ __launch_bounds__(256) void prep_k(
    int* __restrict__ grids, const float* __restrict__ pos,
    const float* __restrict__ in_w1, const float* __restrict__ in_b1,
    const float* __restrict__ out_w1, const float* __restrict__ out_b1,
    const float* __restrict__ in_w2, const float* __restrict__ in_b2,
    const float* __restrict__ out_w2, const float* __restrict__ out_b2,
    float* __restrict__ Wvo, float* __restrict__ pv2g,
    float* __restrict__ obias2) {
  int bx = blockIdx.x;
  if (bx < 800) {
    int i = bx * 256 + threadIdx.x;  // 800*256 int4 = 2*4*HWp ints exactly
    ((int4*)grids)[i] = make_int4(-1, -1, -1, -1);
    return;
  }
  int dir = bx - 800;
  const float* iw = dir == 0 ? in_w1 : in_w2;
  const float* ib = dir == 0 ? in_b1 : in_b2;
  const float* owp = dir == 0 ? out_w1 : out_w2;
  const float* obp = dir == 0 ? out_b1 : out_b2;
  __shared__ float sow[1024], swv[1024], sW[2048];
  int t = threadIdx.x;
  for (int i = t; i < 1024; i += 256) {
    sow[i] = owp[i];
    swv[i] = iw[2 * Cc * Cc + i];  // wv rows of in_w
  }
  __syncthreads();
  for (int e = t; e < 2048; e += 256) {
    int h = e >> 10, idx = e & 1023;
    int c = idx >> 5, j = idx & 31;
    float acc = 0.f;
    for (int jj = 0; jj < 16; jj++)
      acc += sow[c * 32 + h * 16 + jj] * swv[(h * 16 + jj) * 32 + j];
    sW[e] = acc;
    Wvo[dir * 2048 + e] = acc;
  }
  __syncthreads();
  for (int e = t; e < 576; e += 256) {  // 2 heads x 9 slots x 32 ch
    int h = e / 288, rem = e - h * 288;
    int l = rem >> 5, c = rem & 31;
    float acc = 0.f;
    for (int j = 0; j < 32; j++) acc += pos[l * 32 + j] * sW[h * 1024 + c * 32 + j];
    pv2g[dir * 576 + e] = acc;
  }
  if (t < Cc) {
    float acc = obp[t];
    for (int j = 0; j < 32; j++) acc += ib[2 * Cc + j] * sow[t * 32 + j];
    obias2[dir * Cc + t] = acc;
  }
}

// Fused: blocks [0, PROJ_TOTAL) = Q/K/V0f/V1f projection (4 pts/thread, fp16
// stores; V0f/V1f are the per-head folded V); rest = build_grid (pre-filled).
constexpr int PROJ_BLOCKS_PER_SB = 157;              // ceil(20000/128)
constexpr int PROJ_TOTAL = PROJ_BLOCKS_PER_SB * 8;   // 1256
constexpr int BUILD_BLOCKS = 625;                    // 160000/256 exact

__global__ __launch_bounds__(256) void project_build_k(
    const float* __restrict__ li_feats, const float* __restrict__ ra_feats,
    const int* __restrict__ li_coors, const int* __restrict__ ra_coors,
    const float* __restrict__ in_w1, const float* __restrict__ in_b1,
    const float* __restrict__ in_w2, const float* __restrict__ in_b2,
    const float* __restrict__ Wvo,
    __half* __restrict__ Qh, __half* __restrict__ Kp,
    __half* __restrict__ V0, __half* __restrict__ V1,
    int* __restrict__ grids) {
  int bx = blockIdx.x;
  if (bx >= PROJ_TOTAL) {
    int idx = (bx - PROJ_TOTAL) * 256 + threadIdx.x;  // [0, 160000) exact
    int src = idx / (Bb * Nn);
    int r = idx - src * (Bb * Nn);
    int b = r / Nn, n = r - b * Nn;
    const int* c = (src == 0 ? li_coors : ra_coors) + ((size_t)b * Nn + n) * 2;
    grids[((size_t)src * Bb + b) * HWp + c[0] * Ww + c[1]] = n;
    return;
  }
  int sb = bx / PROJ_BLOCKS_PER_SB;
  int blk = bx - sb * PROJ_BLOCKS_PER_SB;
  int src = sb >> 2, b = sb & 3;
  // weights transposed, rows padded to 36 floats (9 float4) for bank spread
  __shared__ __align__(16) float wqT[32 * 36];
  __shared__ __align__(16) float wkT[32 * 36];
  __shared__ __align__(16) float w0T[32 * 36];
  __shared__ __align__(16) float w1T[32 * 36];
  __shared__ float bq[Cc];
  const float* wA = src == 0 ? in_w1 : in_w2;  // q weights: own direction
  const float* bA = src == 0 ? in_b1 : in_b2;
  const float* wB = src == 0 ? in_w2 : in_w1;  // k weights: other direction
  int dirkv = 1 - src;
  const float* Wf = Wvo + (size_t)dirkv * 2048;  // per-head folded V weights
  int t = threadIdx.x;
  for (int i = t; i < Cc * Cc; i += 256) {
    int c = i >> 5, j = i & 31;
    wqT[j * 36 + c] = wA[i];
    wkT[j * 36 + c] = wB[Cc * Cc + i];
    w0T[j * 36 + c] = Wf[i];
    w1T[j * 36 + c] = Wf[1024 + i];
  }
  if (t < Cc) bq[t] = bA[t];
  __syncthreads();
  int quad = t >> 3, c4 = t & 7;
  int n0 = blk * 128 + quad * 4;
  if (n0 + 4 > Nn) n0 = Nn - 4;  // tail clamp: redundant idempotent work
  const float* f = (src == 0 ? li_feats : ra_feats) + ((size_t)b * Nn + n0) * Cc;
  const float4* wq4 = (const float4*)wqT;
  const float4* wk4 = (const float4*)wkT;
  const float4* w04 = (const float4*)w0T;
  const float4* w14 = (const float4*)w1T;
  float4 bq4 = *(const float4*)(bq + c4 * 4);
  float4 aq[4], ak[4], a0[4], a1[4];
#pragma unroll
  for (int i = 0; i < 4; i++) {
    aq[i] = bq4;
    ak[i] = make_float4(0.f, 0.f, 0.f, 0.f);
    a0[i] = make_float4(0.f, 0.f, 0.f, 0.f);
    a1[i] = make_float4(0.f, 0.f, 0.f, 0.f);
  }
#pragma unroll
  for (int j4 = 0; j4 < 8; j4++) {
    float fjs[4][4];
#pragma unroll
    for (int i = 0; i < 4; i++) {
      float4 v = ((const float4*)(f + i * Cc))[j4];
      fjs[i][0] = v.x; fjs[i][1] = v.y; fjs[i][2] = v.z; fjs[i][3] = v.w;
    }
#pragma unroll
    for (int u = 0; u < 4; u++) {
      int j = j4 * 4 + u;
      float4 q4 = wq4[j * 9 + c4];
      float4 k4 = wk4[j * 9 + c4];
      float4 v04 = w04[j * 9 + c4];
      float4 v14 = w14[j * 9 + c4];
#pragma unroll
      for (int i = 0; i < 4; i++) {
        float fj = fjs[i][u];
        aq[i].x += fj * q4.x; aq[i].y += fj * q4.y;
        aq[i].z += fj * q4.z; aq[i].w += fj * q4.w;
        ak[i].x += fj * k4.x; ak[i].y += fj * k4.y;
        ak[i].z += fj * k4.z; ak[i].w += fj * k4.w;
        a0[i].x += fj * v04.x; a0[i].y += fj * v04.y;
        a0[i].z += fj * v04.z; a0[i].w += fj * v04.w;
        a1[i].x += fj * v14.x; a1[i].y += fj * v14.y;
        a1[i].z += fj * v14.z; a1[i].w += fj * v14.w;
      }
    }
  }
  size_t qbase = (((size_t)src * Bb + b) * Nn + n0) * Cc + c4 * 4;
  size_t kvbase = (((size_t)dirkv * Bb + b) * Nn + n0) * Cc + c4 * 4;
#pragma unroll
  for (int i = 0; i < 4; i++) {
    store_h4(Qh + qbase + i * Cc, aq[i]);
    store_h4(Kp + kvbase + i * Cc, ak[i]);
    store_h4(V0 + kvbase + i * Cc, a0[i]);
    store_h4(V1 + kvbase + i * Cc, a1[i]);
  }
}

// 8-lane-per-point attention with folded output projection.
// XCD-partitioned: db = blockIdx.x % 8 so all blocks of one (dir,b) land on
// one XCD (round-robin dispatch) -> its K/V0/V1 slices (~3.8 MB, 9x reuse)
// stay resident in that XCD's 4 MB L2; gathers become L2-hits instead of L3.
__global__ __launch_bounds__(256) void attn8_k(
    const int* __restrict__ li_coors, const int* __restrict__ ra_coors,
    const int* __restrict__ grids, const __half* __restrict__ Qh,
    const __half* __restrict__ Kp, const __half* __restrict__ V0,
    const __half* __restrict__ V1, const float* __restrict__ pv2g,
    const float* __restrict__ in_b1, const float* __restrict__ in_b2,
    const float* __restrict__ obias2, __half* __restrict__ out_pts) {
  int db = blockIdx.x & 7;   // XCD-pinned (dir,b)
  int bx = blockIdx.x >> 3;  // point tile [0, 625)
  int dir = db >> 2, b = db & 3;
  __shared__ __align__(16) float spv[576];  // [h][l][c]
  __shared__ float sbk[Cc], sob[Cc];
  const float* ibp = dir == 0 ? in_b1 : in_b2;
  int t = threadIdx.x;
  for (int i = t; i < 576; i += 256) spv[i] = pv2g[dir * 576 + i];
  if (t < Cc) {
    sbk[t] = ibp[Cc + t];
    sob[t] = obias2[dir * Cc + t];
  }
  __syncthreads();
  int pt = t >> 3, c4 = t & 7;
  int n = bx * 32 + pt;  // 625*32 == 20000 exact, no tail
  const int2* qcp =
      (const int2*)((dir == 0 ? li_coors : ra_coors) + (size_t)b * Nn * 2);
  int2 yx = qcp[n];
  int y = yx.x, x = yx.y;
  const int* g = grids + ((size_t)(1 - dir) * Bb + b) * HWp;
  const int DY[9] = {0, -1, 1, 0, -1, 1, 0, -1, 1};
  const int DX[9] = {0, 0, 0, 1, 1, 1, -1, -1, -1};
  // ---- phase 1: all 9 sel loads (independent, 1-deep; grid pre-filled)
  int sel[9];
#pragma unroll
  for (int l = 0; l < 9; l++) {
    int cy = y + DY[l], cx = x + DX[l];
    sel[l] = ((unsigned)cy < (unsigned)Hh && (unsigned)cx < (unsigned)Ww)
                 ? g[cy * Ww + cx]
                 : -1;
  }
  // ---- phase 2: issue all K/V0/V1 gathers (raw fp16, 8B/lane; 0 if invalid)
  size_t dbb = ((size_t)dir * Bb + b) * Nn * Cc;
  const __half* Kpb = Kp + dbb;
  const __half* V0b = V0 + dbb;
  const __half* V1b = V1 + dbb;
  float2 kr[9], v0r[9], v1r[9];
#pragma unroll
  for (int l = 0; l < 9; l++) {
    float2 kk = make_float2(0.f, 0.f);  // bit pattern 0 == fp16 zeros
    float2 v0v = make_float2(0.f, 0.f);
    float2 v1v = make_float2(0.f, 0.f);
    int se = sel[l];
    if (se >= 0) {
      size_t o = (size_t)se * Cc + c4 * 4;
      kk = *(const float2*)(Kpb + o);
      v0v = *(const float2*)(V0b + o);
      v1v = *(const float2*)(V1b + o);
    }
    kr[l] = kk;
    v0r[l] = v0v;
    v1r[l] = v1v;
  }
  float4 qh4 = cvt_h4(
      *(const float2*)(Qh + (((size_t)dir * Bb + b) * Nn + n) * Cc + c4 * 4));
  // invalid-slot score: qh . bk over the lane's head (DPP quad reduce)
  float4 bk4 = *(const float4*)(sbk + c4 * 4);
  float pb = qh4.x * bk4.x + qh4.y * bk4.y + qh4.z * bk4.z + qh4.w * bk4.w;
  pb = quad_add_xor1(pb);
  pb = quad_add_xor2(pb);
  // ---- phase 3: scores (own head) from registers
  float s[9];
#pragma unroll
  for (int l = 0; l < 9; l++) {
    float4 k4 = cvt_h4(kr[l]);
    float d = qh4.x * k4.x + qh4.y * k4.y + qh4.z * k4.z + qh4.w * k4.w;
    d = quad_add_xor1(d);
    d = quad_add_xor2(d);
    s[l] = 0.25f * (pb + d);
  }
  // softmax over 9 slots for the lane's head (invalid slots participate: s=pb/4)
  float m = s[0];
#pragma unroll
  for (int l = 1; l < 9; l++) m = fmaxf(m, s[l]);
  float sum = 0.f;
#pragma unroll
  for (int l = 0; l < 9; l++) {
    s[l] = __expf(s[l] - m);
    sum += s[l];
  }
  float rsum = 1.f / sum;
  float aown[9], aoth[9];
#pragma unroll
  for (int l = 0; l < 9; l++) aown[l] = s[l] * rsum;
#pragma unroll
  for (int l = 0; l < 9; l++) aoth[l] = __shfl_xor(aown[l], 4);
  // ---- phase 4: dual-head PV; lane's out channels = [4*c4..). hd = own head.
  int hd = c4 >> 2;
  float4 acc = *(const float4*)(sob + c4 * 4);  // out_b + B0 + B1
  const float* pv0 = spv + 0 * 288 + c4 * 4;
  const float* pv1 = spv + 1 * 288 + c4 * 4;
#pragma unroll
  for (int l = 0; l < 9; l++) {
    if (sel[l] >= 0) {
      float a0w = hd == 0 ? aown[l] : aoth[l];
      float a1w = hd == 0 ? aoth[l] : aown[l];
      float4 v0 = cvt_h4(v0r[l]);
      float4 v1 = cvt_h4(v1r[l]);
      float4 p0 = *(const float4*)(pv0 + l * 32);
      float4 p1 = *(const float4*)(pv1 + l * 32);
      acc.x += a0w * (v0.x + p0.x) + a1w * (v1.x + p1.x);
      acc.y += a0w * (v0.y + p0.y) + a1w * (v1.y + p1.y);
      acc.z += a0w * (v0.z + p0.z) + a1w * (v1.z + p1.z);
      acc.w += a0w * (v0.w + p0.w) + a1w * (v1.w + p1.w);
    }
  }
  store_h4(out_pts + (((size_t)dir * Bb + b) * Nn + n) * Cc + c4 * 4, acc);
}

// Inverted scatter, XCD-partitioned like attn8 (out_pts slice L2-resident).
// One thread per canvas pixel; every pixel written (full-line coverage --
// r19 lesson: never split a dense store range by data-dependent predicate).
__global__ __launch_bounds__(256) void scatter_k(
    const int* __restrict__ grids, const __half* __restrict__ out_pts,
    float* __restrict__ out) {
  int db = blockIdx.x & 7;   // XCD-pinned (dir,b)
  int bx = blockIdx.x >> 3;  // pixel tile [0, 400)
  int dir = db >> 2, b = db & 3;
  int p = bx * 256 + threadIdx.x;
  const int* gq = grids + ((size_t)dir * Bb + b) * HWp;
  int se = gq[p];
  float* ob = out + (((size_t)dir * Bb + b) * Cc) * HWp + p;
  if (se < 0) {
#pragma unroll
    for (int c = 0; c < Cc; c++) ob[(size_t)c * HWp] = 0.f;
  } else {
    const float4* sp =
        (const float4*)(out_pts + (((size_t)dir * Bb + b) * Nn + se) * Cc);
#pragma unroll
    for (int c8 = 0; c8 < 4; c8++) {
      H8 u;
      u.f4 = sp[c8];
#pragma unroll
      for (int k = 0; k < 4; k++) {
        float2 pr = __half22float2(u.h2[k]);
        ob[(size_t)(c8 * 8 + k * 2 + 0) * HWp] = pr.x;
        ob[(size_t)(c8 * 8 + k * 2 + 1) * HWp] = pr.y;
      }
    }
  }
}

extern "C" void kernel_launch(void* const* d_in, const int* in_sizes, int n_in,
                              void* d_out, int out_size, void* d_ws, size_t ws_size,
                              hipStream_t stream) {
  const float* li_feats = (const float*)d_in[0];
  const int* li_coors = (const int*)d_in[1];
  const float* ra_feats = (const float*)d_in[2];
  const int* ra_coors = (const int*)d_in[3];
  const float* pos = (const float*)d_in[4];
  const float* in_w1 = (const float*)d_in[5];
  const float* in_b1 = (const float*)d_in[6];
  const float* out_w1 = (const float*)d_in[7];
  const float* out_b1 = (const float*)d_in[8];
  const float* in_w2 = (const float*)d_in[9];
  const float* in_b2 = (const float*)d_in[10];
  const float* out_w2 = (const float*)d_in[11];
  const float* out_b2 = (const float*)d_in[12];

  char* ws = (char*)d_ws;
  size_t off = 0;
  int* grids = (int*)(ws + off);
  off += (size_t)2 * Bb * HWp * 4;  // 3,276,800 B
  __half* Qh = (__half*)(ws + off);
  off += (size_t)2 * Bb * Nn * Cc * 2;  // 10,240,000 B
  __half* Kp = (__half*)(ws + off);
  off += (size_t)2 * Bb * Nn * Cc * 2;
  __half* V0 = (__half*)(ws + off);
  off += (size_t)2 * Bb * Nn * Cc * 2;
  __half* V1 = (__half*)(ws + off);
  off += (size_t)2 * Bb * Nn * Cc * 2;
  __half* out_pts = (__half*)(ws + off);
  off += (size_t)2 * Bb * Nn * Cc * 2;
  float* Wvo = (float*)(ws + off);
  off += 2 * 2048 * 4;
  float* pv2g = (float*)(ws + off);
  off += 2 * 576 * 4;
  float* obias2 = (float*)(ws + off);
  off += 2 * Cc * 4;  // total ~54.5 MB

  prep_k<<<802, 256, 0, stream>>>(grids, pos, in_w1, in_b1, out_w1, out_b1,
                                  in_w2, in_b2, out_w2, out_b2, Wvo, pv2g,
                                  obias2);
  project_build_k<<<PROJ_TOTAL + BUILD_BLOCKS, 256, 0, stream>>>(
      li_feats, ra_feats, li_coors, ra_coors, in_w1, in_b1, in_w2, in_b2, Wvo,
      Qh, Kp, V0, V1, grids);
  attn8_k<<<(Nn / 32) * 8, 256, 0, stream>>>(li_coors, ra_coors, grids, Qh, Kp,
                                             V0, V1, pv2g, in_b1, in_b2, obias2,
                                             out_pts);
  scatter_k<<<(HWp / 256) * 8, 256, 0, stream>>>(grids, out_pts,
                                                 (float*)d_out);
}